// Round 1
// baseline (842.551 us; speedup 1.0000x reference)
//
#include <hip/hip_runtime.h>
#include <math.h>

#define BB   16
#define C    128
#define C4   32
#define NN   2304          // 48*48
#define BN_EPS 1e-5f
#define NEG_INF -3.402823466e38f

// ---------------- workspace layout (floats) ----------------
// Kf  [16][32][2304]   @ 0            (1179648)
// Qf  [16][32][2304]   @ 1179648      (1179648)
// Vf  [16][128][2304]  @ 2359296      (4718592)
// bmax[16*1296]        @ 7077888      (20736)
// bsum[16*1296]        @ 7098624      (20736)
// Ms  [16]             @ 7119360
// Sinv[16]             @ 7119376

// K/Q conv: out[b,k,n] = relu(bn(sum_c w[k,c]*x[b,c,n])), k<32, c<128
__global__ __launch_bounds__(256) void k_kq(
    const float* __restrict__ xen, const float* __restrict__ xde,
    const float* __restrict__ w,  const float* __restrict__ g,
    const float* __restrict__ be, const float* __restrict__ mu,
    const float* __restrict__ va, float* __restrict__ Kf, float* __restrict__ Qf)
{
    __shared__ float ws[C4][C];   // 16 KB
    const int tid = threadIdx.x;
    for (int i = tid; i < C4 * C; i += 256) ws[i / C][i % C] = w[i];
    __syncthreads();

    const int n = blockIdx.x * 256 + tid;
    const int b = blockIdx.y;
    const float* x  = blockIdx.z ? xde : xen;
    float*      out = blockIdx.z ? Qf  : Kf;
    const float* xb = x + (size_t)b * C * NN + n;

    float acc[C4];
#pragma unroll
    for (int k = 0; k < C4; k++) acc[k] = 0.f;

    for (int c0 = 0; c0 < C; c0 += 4) {
        const float x0 = xb[(c0 + 0) * NN];
        const float x1 = xb[(c0 + 1) * NN];
        const float x2 = xb[(c0 + 2) * NN];
        const float x3 = xb[(c0 + 3) * NN];
#pragma unroll
        for (int k = 0; k < C4; k++) {
            const float4 wv = *(const float4*)&ws[k][c0];
            acc[k] = fmaf(wv.x, x0, acc[k]);
            acc[k] = fmaf(wv.y, x1, acc[k]);
            acc[k] = fmaf(wv.z, x2, acc[k]);
            acc[k] = fmaf(wv.w, x3, acc[k]);
        }
    }
    float* ob = out + (size_t)b * C4 * NN + n;
#pragma unroll
    for (int k = 0; k < C4; k++) {
        const float sc = g[k] * rsqrtf(va[k] + BN_EPS);
        const float v  = fmaf(acc[k], sc, be[k] - mu[k] * sc);
        ob[k * NN] = v > 0.f ? v : 0.f;
    }
}

// reduce conv: x[b,o,n] = relu(bn(sum_{c<256} w[o,c]*xcat[b,c,n])) -> d_out ch 0..127
__global__ __launch_bounds__(256) void k_red(
    const float* __restrict__ xcat, const float* __restrict__ w,
    const float* __restrict__ g,  const float* __restrict__ be,
    const float* __restrict__ mu, const float* __restrict__ va,
    float* __restrict__ out)
{
    __shared__ float ws[32][2 * C];   // 32 KB
    const int tid = threadIdx.x;
    const int ob  = blockIdx.z;       // 0..3 -> output chans ob*32..+31
    const float* wrow = w + (size_t)ob * 32 * (2 * C);
    for (int i = tid; i < 32 * 2 * C; i += 256) ws[i / (2 * C)][i % (2 * C)] = wrow[i];
    __syncthreads();

    const int n = blockIdx.x * 256 + tid;
    const int b = blockIdx.y;
    const float* xb = xcat + (size_t)b * 2 * C * NN + n;

    float acc[32];
#pragma unroll
    for (int k = 0; k < 32; k++) acc[k] = 0.f;

    for (int c0 = 0; c0 < 2 * C; c0 += 4) {
        const float x0 = xb[(c0 + 0) * NN];
        const float x1 = xb[(c0 + 1) * NN];
        const float x2 = xb[(c0 + 2) * NN];
        const float x3 = xb[(c0 + 3) * NN];
#pragma unroll
        for (int k = 0; k < 32; k++) {
            const float4 wv = *(const float4*)&ws[k][c0];
            acc[k] = fmaf(wv.x, x0, acc[k]);
            acc[k] = fmaf(wv.y, x1, acc[k]);
            acc[k] = fmaf(wv.z, x2, acc[k]);
            acc[k] = fmaf(wv.w, x3, acc[k]);
        }
    }
    float* obp = out + (size_t)b * 2 * C * NN + n;
#pragma unroll
    for (int k = 0; k < 32; k++) {
        const int o = ob * 32 + k;
        const float sc = g[o] * rsqrtf(va[o] + BN_EPS);
        const float v  = fmaf(acc[k], sc, be[o] - mu[o] * sc);
        obp[o * NN] = v > 0.f ? v : 0.f;
    }
}

// V conv: V[b,o,n] = relu(bn(sum_{c<128} w[o,c]*x[b,c,n])), x read from d_out ch 0..127
__global__ __launch_bounds__(256) void k_v(
    const float* __restrict__ xall, const float* __restrict__ w,
    const float* __restrict__ g,  const float* __restrict__ be,
    const float* __restrict__ mu, const float* __restrict__ va,
    float* __restrict__ Vf)
{
    __shared__ float ws[32][C];   // 16 KB
    const int tid = threadIdx.x;
    const int ob  = blockIdx.z;   // 0..3
    const float* wrow = w + (size_t)ob * 32 * C;
    for (int i = tid; i < 32 * C; i += 256) ws[i / C][i % C] = wrow[i];
    __syncthreads();

    const int n = blockIdx.x * 256 + tid;
    const int b = blockIdx.y;
    const float* xb = xall + (size_t)b * 2 * C * NN + n;   // channels 0..127 of out

    float acc[32];
#pragma unroll
    for (int k = 0; k < 32; k++) acc[k] = 0.f;

    for (int c0 = 0; c0 < C; c0 += 4) {
        const float x0 = xb[(c0 + 0) * NN];
        const float x1 = xb[(c0 + 1) * NN];
        const float x2 = xb[(c0 + 2) * NN];
        const float x3 = xb[(c0 + 3) * NN];
#pragma unroll
        for (int k = 0; k < 32; k++) {
            const float4 wv = *(const float4*)&ws[k][c0];
            acc[k] = fmaf(wv.x, x0, acc[k]);
            acc[k] = fmaf(wv.y, x1, acc[k]);
            acc[k] = fmaf(wv.z, x2, acc[k]);
            acc[k] = fmaf(wv.w, x3, acc[k]);
        }
    }
    float* ob_p = Vf + (size_t)b * C * NN + n;
#pragma unroll
    for (int k = 0; k < 32; k++) {
        const int o = ob * 32 + k;
        const float sc = g[o] * rsqrtf(va[o] + BN_EPS);
        const float v  = fmaf(acc[k], sc, be[o] - mu[o] * sc);
        ob_p[o * NN] = v > 0.f ? v : 0.f;
    }
}

// stats pass: 64x64 KQ tile per block; per-block max and sum(exp(kq - blockmax))
__global__ __launch_bounds__(256) void k_stats(
    const float* __restrict__ Kf, const float* __restrict__ Qf,
    float* __restrict__ bmax, float* __restrict__ bsum)
{
    __shared__ float Kt[32][68];
    __shared__ float Qt[32][68];
    __shared__ float red[256];
    const int tid = threadIdx.x;
    const int b  = blockIdx.z;
    const int n0 = blockIdx.x * 64, m0 = blockIdx.y * 64;
    const float* Kb = Kf + (size_t)b * C4 * NN;
    const float* Qb = Qf + (size_t)b * C4 * NN;

    {
        const int k = tid >> 4, nq = tid & 15;
#pragma unroll
        for (int s = 0; s < 2; s++) {
            const int kk = k + 16 * s;
            *(float4*)&Kt[kk][nq * 4] = *(const float4*)&Kb[(size_t)kk * NN + n0 + nq * 4];
            *(float4*)&Qt[kk][nq * 4] = *(const float4*)&Qb[(size_t)kk * NN + m0 + nq * 4];
        }
    }
    __syncthreads();

    const int txn = tid & 15, tym = tid >> 4;
    float acc[4][4];
#pragma unroll
    for (int i = 0; i < 4; i++)
#pragma unroll
        for (int j = 0; j < 4; j++) acc[i][j] = 0.f;

#pragma unroll 8
    for (int k = 0; k < 32; k++) {
        const float4 kv = *(const float4*)&Kt[k][txn * 4];
        const float4 qv = *(const float4*)&Qt[k][tym * 4];
        const float qa[4] = {qv.x, qv.y, qv.z, qv.w};
        const float ka[4] = {kv.x, kv.y, kv.z, kv.w};
#pragma unroll
        for (int mi = 0; mi < 4; mi++)
#pragma unroll
            for (int ni = 0; ni < 4; ni++)
                acc[mi][ni] = fmaf(qa[mi], ka[ni], acc[mi][ni]);
    }

    float lm = NEG_INF;
#pragma unroll
    for (int mi = 0; mi < 4; mi++)
#pragma unroll
        for (int ni = 0; ni < 4; ni++) lm = fmaxf(lm, acc[mi][ni]);
    red[tid] = lm;
    __syncthreads();
    for (int s = 128; s > 0; s >>= 1) {
        if (tid < s) red[tid] = fmaxf(red[tid], red[tid + s]);
        __syncthreads();
    }
    const float bm = red[0];
    __syncthreads();

    float ls = 0.f;
#pragma unroll
    for (int mi = 0; mi < 4; mi++)
#pragma unroll
        for (int ni = 0; ni < 4; ni++) ls += __expf(acc[mi][ni] - bm);
    red[tid] = ls;
    __syncthreads();
    for (int s = 128; s > 0; s >>= 1) {
        if (tid < s) red[tid] += red[tid + s];
        __syncthreads();
    }
    if (tid == 0) {
        const int idx = b * 1296 + blockIdx.y * 36 + blockIdx.x;
        bmax[idx] = bm;
        bsum[idx] = red[0];
    }
}

// finalize: per-batch global max + sum -> Ms, Sinv
__global__ __launch_bounds__(256) void k_fin(
    const float* __restrict__ bmax, const float* __restrict__ bsum,
    float* __restrict__ Ms, float* __restrict__ Sinv)
{
    __shared__ float red[256];
    const int b = blockIdx.x, tid = threadIdx.x;
    float lm = NEG_INF;
    for (int i = tid; i < 1296; i += 256) lm = fmaxf(lm, bmax[b * 1296 + i]);
    red[tid] = lm;
    __syncthreads();
    for (int s = 128; s > 0; s >>= 1) {
        if (tid < s) red[tid] = fmaxf(red[tid], red[tid + s]);
        __syncthreads();
    }
    const float M = red[0];
    __syncthreads();
    float ls = 0.f;
    for (int i = tid; i < 1296; i += 256)
        ls += bsum[b * 1296 + i] * __expf(bmax[b * 1296 + i] - M);
    red[tid] = ls;
    __syncthreads();
    for (int s = 128; s > 0; s >>= 1) {
        if (tid < s) red[tid] += red[tid + s];
        __syncthreads();
    }
    if (tid == 0) { Ms[b] = M; Sinv[b] = 1.f / red[0]; }
}

// feat pass: block computes 128(c) x 32(n) output tile; loop m in chunks of 32,
// recompute E = exp(KQ - M)/S tile, accumulate feat[c,n] += V[c,m]*E[m,n]
__global__ __launch_bounds__(256) void k_feat(
    const float* __restrict__ Kf, const float* __restrict__ Qf,
    const float* __restrict__ Vf, const float* __restrict__ Ms,
    const float* __restrict__ Sinv, float* __restrict__ out)
{
    __shared__ float Kt[32][36];   // [k][n]  b128-read, 4-aligned pad
    __shared__ float Qt[32][33];   // [k][m]  scalar-read, odd pad
    __shared__ float Et[32][40];   // [m][n]  b128 r/w, conflict-free pad
    __shared__ float Vt[128][37];  // [c][m]  scalar-read, odd pad
    const int tid = threadIdx.x;
    const int b = blockIdx.y, n0 = blockIdx.x * 32;
    const float* Kb = Kf + (size_t)b * C4 * NN;
    const float* Qb = Qf + (size_t)b * C4 * NN;
    const float* Vb = Vf + (size_t)b * C * NN;

    {   // stage K tile once (block's 32 n's)
        const int k = tid >> 3, q = tid & 7;
        *(float4*)&Kt[k][q * 4] = *(const float4*)&Kb[(size_t)k * NN + n0 + q * 4];
    }
    const float M  = Ms[b];
    const float Si = Sinv[b];

    float acc[4][4];
#pragma unroll
    for (int i = 0; i < 4; i++)
#pragma unroll
        for (int j = 0; j < 4; j++) acc[i][j] = 0.f;

    const int tx = tid & 7;    // n-quad (n = tx*4..+3)
    const int ty = tid >> 3;   // c-quad (c = ty*4..+3) / E-row m index

    for (int m0 = 0; m0 < NN; m0 += 32) {
        __syncthreads();
        {   // stage Q tile [32k][32m]
            const int k = tid >> 3, q = tid & 7;
            const float4 qv = *(const float4*)&Qb[(size_t)k * NN + m0 + q * 4];
            Qt[k][q * 4 + 0] = qv.x; Qt[k][q * 4 + 1] = qv.y;
            Qt[k][q * 4 + 2] = qv.z; Qt[k][q * 4 + 3] = qv.w;
        }
        {   // stage V tile [128c][32m]
            const int q = tid & 7, cb = tid >> 3;
#pragma unroll
            for (int s = 0; s < 4; s++) {
                const int c = cb + s * 32;
                const float4 vv = *(const float4*)&Vb[(size_t)c * NN + m0 + q * 4];
                Vt[c][q * 4 + 0] = vv.x; Vt[c][q * 4 + 1] = vv.y;
                Vt[c][q * 4 + 2] = vv.z; Vt[c][q * 4 + 3] = vv.w;
            }
        }
        __syncthreads();
        {   // E tile: thread computes E[ty][tx*4..+3]
            float4 e = make_float4(0.f, 0.f, 0.f, 0.f);
#pragma unroll 8
            for (int k = 0; k < 32; k++) {
                const float qv = Qt[k][ty];
                const float4 kv = *(const float4*)&Kt[k][tx * 4];
                e.x = fmaf(qv, kv.x, e.x); e.y = fmaf(qv, kv.y, e.y);
                e.z = fmaf(qv, kv.z, e.z); e.w = fmaf(qv, kv.w, e.w);
            }
            float4 E4;
            E4.x = __expf(e.x - M) * Si; E4.y = __expf(e.y - M) * Si;
            E4.z = __expf(e.z - M) * Si; E4.w = __expf(e.w - M) * Si;
            *(float4*)&Et[ty][tx * 4] = E4;
        }
        __syncthreads();
        // main accumulation: acc[ci][ni] += V[ty*4+ci][j] * E[j][tx*4+ni]
#pragma unroll 4
        for (int j = 0; j < 32; j++) {
            const float4 e4 = *(const float4*)&Et[j][tx * 4];
            const float v0 = Vt[ty * 4 + 0][j];
            const float v1 = Vt[ty * 4 + 1][j];
            const float v2 = Vt[ty * 4 + 2][j];
            const float v3 = Vt[ty * 4 + 3][j];
            acc[0][0] = fmaf(v0, e4.x, acc[0][0]); acc[0][1] = fmaf(v0, e4.y, acc[0][1]);
            acc[0][2] = fmaf(v0, e4.z, acc[0][2]); acc[0][3] = fmaf(v0, e4.w, acc[0][3]);
            acc[1][0] = fmaf(v1, e4.x, acc[1][0]); acc[1][1] = fmaf(v1, e4.y, acc[1][1]);
            acc[1][2] = fmaf(v1, e4.z, acc[1][2]); acc[1][3] = fmaf(v1, e4.w, acc[1][3]);
            acc[2][0] = fmaf(v2, e4.x, acc[2][0]); acc[2][1] = fmaf(v2, e4.y, acc[2][1]);
            acc[2][2] = fmaf(v2, e4.z, acc[2][2]); acc[2][3] = fmaf(v2, e4.w, acc[2][3]);
            acc[3][0] = fmaf(v3, e4.x, acc[3][0]); acc[3][1] = fmaf(v3, e4.y, acc[3][1]);
            acc[3][2] = fmaf(v3, e4.z, acc[3][2]); acc[3][3] = fmaf(v3, e4.w, acc[3][3]);
        }
    }

    // epilogue: feat goes to output channels 128..255
    float* ob = out + (size_t)b * 2 * C * NN + (size_t)C * NN + n0;
#pragma unroll
    for (int i = 0; i < 4; i++) {
        const int c = ty * 4 + i;
        float4 r;
        r.x = acc[i][0]; r.y = acc[i][1]; r.z = acc[i][2]; r.w = acc[i][3];
        *(float4*)&ob[(size_t)c * NN + tx * 4] = r;
    }
}

extern "C" void kernel_launch(void* const* d_in, const int* in_sizes, int n_in,
                              void* d_out, int out_size, void* d_ws, size_t ws_size,
                              hipStream_t stream)
{
    const float* x_en   = (const float*)d_in[0];
    const float* x_de   = (const float*)d_in[1];
    const float* x_cat  = (const float*)d_in[2];
    const float* w_kq   = (const float*)d_in[3];
    const float* kq_g   = (const float*)d_in[4];
    const float* kq_b   = (const float*)d_in[5];
    const float* kq_m   = (const float*)d_in[6];
    const float* kq_v   = (const float*)d_in[7];
    const float* w_v    = (const float*)d_in[8];
    const float* v_g    = (const float*)d_in[9];
    const float* v_b    = (const float*)d_in[10];
    const float* v_m    = (const float*)d_in[11];
    const float* v_v    = (const float*)d_in[12];
    const float* w_red  = (const float*)d_in[13];
    const float* red_g  = (const float*)d_in[14];
    const float* red_b  = (const float*)d_in[15];
    const float* red_m  = (const float*)d_in[16];
    const float* red_v  = (const float*)d_in[17];

    float* ws   = (float*)d_ws;
    float* Kf   = ws;
    float* Qf   = ws + 1179648;
    float* Vf   = ws + 2359296;
    float* bmax = ws + 7077888;
    float* bsum = bmax + 20736;
    float* Ms   = bsum + 20736;
    float* Sinv = Ms + 16;
    float* out  = (float*)d_out;

    k_kq  <<<dim3(9, 16, 2), 256, 0, stream>>>(x_en, x_de, w_kq, kq_g, kq_b, kq_m, kq_v, Kf, Qf);
    k_red <<<dim3(9, 16, 4), 256, 0, stream>>>(x_cat, w_red, red_g, red_b, red_m, red_v, out);
    k_v   <<<dim3(9, 16, 4), 256, 0, stream>>>(out, w_v, v_g, v_b, v_m, v_v, Vf);
    k_stats<<<dim3(36, 36, 16), 256, 0, stream>>>(Kf, Qf, bmax, bsum);
    k_fin <<<16, 256, 0, stream>>>(bmax, bsum, Ms, Sinv);
    k_feat<<<dim3(72, 16), 256, 0, stream>>>(Kf, Qf, Vf, Ms, Sinv, out);
}

// Round 2
// 393.020 us; speedup vs baseline: 2.1438x; 2.1438x over previous
//
#include <hip/hip_runtime.h>
#include <math.h>

#define C    128
#define C4   32
#define NN   2304          // 48*48
#define BN_EPS 1e-5f
#define NEG_INF -3.402823466e38f

typedef short bf16x8 __attribute__((ext_vector_type(8)));
typedef float f32x4 __attribute__((ext_vector_type(4)));

__device__ inline unsigned short f2bf(float f) {
    unsigned int u = __float_as_uint(f);
    u += 0x7fffu + ((u >> 16) & 1u);
    return (unsigned short)(u >> 16);
}

// ---------------- workspace layout ----------------
// Kt  [16][2304][32] bf16  (K transposed: k contiguous)   1179648 ushort
// Qt  [16][2304][32] bf16                                 1179648 ushort
// Vf  [16][128][2304] bf16 (m contiguous)                 4718592 ushort
// bmax[16*324] f32, bsum[16*324] f32, Ms[16], Sinv[16]

// K/Q conv (fp32 compute) -> bf16 transposed outputs
__global__ __launch_bounds__(256) void k_kq(
    const float* __restrict__ xen, const float* __restrict__ xde,
    const float* __restrict__ w,  const float* __restrict__ g,
    const float* __restrict__ be, const float* __restrict__ mu,
    const float* __restrict__ va, unsigned short* __restrict__ Kt,
    unsigned short* __restrict__ Qt)
{
    __shared__ float ws[C4][C];
    const int tid = threadIdx.x;
    for (int i = tid; i < C4 * C; i += 256) ws[i / C][i % C] = w[i];
    __syncthreads();

    const int n = blockIdx.x * 256 + tid;
    const int b = blockIdx.y;
    const float* x = blockIdx.z ? xde : xen;
    const float* xb = x + (size_t)b * C * NN + n;

    float acc[C4];
#pragma unroll
    for (int k = 0; k < C4; k++) acc[k] = 0.f;

    for (int c0 = 0; c0 < C; c0 += 4) {
        const float x0 = xb[(c0 + 0) * NN];
        const float x1 = xb[(c0 + 1) * NN];
        const float x2 = xb[(c0 + 2) * NN];
        const float x3 = xb[(c0 + 3) * NN];
#pragma unroll
        for (int k = 0; k < C4; k++) {
            const float4 wv = *(const float4*)&ws[k][c0];
            acc[k] = fmaf(wv.x, x0, acc[k]);
            acc[k] = fmaf(wv.y, x1, acc[k]);
            acc[k] = fmaf(wv.z, x2, acc[k]);
            acc[k] = fmaf(wv.w, x3, acc[k]);
        }
    }
    unsigned int pk[16];
#pragma unroll
    for (int k = 0; k < C4; k += 2) {
        const float sc0 = g[k] * rsqrtf(va[k] + BN_EPS);
        float v0 = fmaf(acc[k], sc0, be[k] - mu[k] * sc0);
        const float sc1 = g[k + 1] * rsqrtf(va[k + 1] + BN_EPS);
        float v1 = fmaf(acc[k + 1], sc1, be[k + 1] - mu[k + 1] * sc1);
        v0 = v0 > 0.f ? v0 : 0.f;
        v1 = v1 > 0.f ? v1 : 0.f;
        pk[k >> 1] = (unsigned int)f2bf(v0) | ((unsigned int)f2bf(v1) << 16);
    }
    unsigned short* obp = (blockIdx.z ? Qt : Kt) + ((size_t)b * NN + n) * 32;
#pragma unroll
    for (int q = 0; q < 4; q++)
        *(uint4*)&obp[q * 8] = make_uint4(pk[4 * q], pk[4 * q + 1], pk[4 * q + 2], pk[4 * q + 3]);
}

// reduce conv (fp32): x = relu(bn(w_red * x_cat)) -> d_out channels 0..127
__global__ __launch_bounds__(256) void k_red(
    const float* __restrict__ xcat, const float* __restrict__ w,
    const float* __restrict__ g,  const float* __restrict__ be,
    const float* __restrict__ mu, const float* __restrict__ va,
    float* __restrict__ out)
{
    __shared__ float ws[32][2 * C];
    const int tid = threadIdx.x;
    const int obk = blockIdx.z;
    const float* wrow = w + (size_t)obk * 32 * (2 * C);
    for (int i = tid; i < 32 * 2 * C; i += 256) ws[i / (2 * C)][i % (2 * C)] = wrow[i];
    __syncthreads();

    const int n = blockIdx.x * 256 + tid;
    const int b = blockIdx.y;
    const float* xb = xcat + (size_t)b * 2 * C * NN + n;

    float acc[32];
#pragma unroll
    for (int k = 0; k < 32; k++) acc[k] = 0.f;

    for (int c0 = 0; c0 < 2 * C; c0 += 4) {
        const float x0 = xb[(c0 + 0) * NN];
        const float x1 = xb[(c0 + 1) * NN];
        const float x2 = xb[(c0 + 2) * NN];
        const float x3 = xb[(c0 + 3) * NN];
#pragma unroll
        for (int k = 0; k < 32; k++) {
            const float4 wv = *(const float4*)&ws[k][c0];
            acc[k] = fmaf(wv.x, x0, acc[k]);
            acc[k] = fmaf(wv.y, x1, acc[k]);
            acc[k] = fmaf(wv.z, x2, acc[k]);
            acc[k] = fmaf(wv.w, x3, acc[k]);
        }
    }
    float* obp = out + (size_t)b * 2 * C * NN + n;
#pragma unroll
    for (int k = 0; k < 32; k++) {
        const int o = obk * 32 + k;
        const float sc = g[o] * rsqrtf(va[o] + BN_EPS);
        const float v  = fmaf(acc[k], sc, be[o] - mu[o] * sc);
        obp[o * NN] = v > 0.f ? v : 0.f;
    }
}

// V conv (fp32 compute, reads x from d_out ch 0..127) -> bf16 Vf [b][c][m]
__global__ __launch_bounds__(256) void k_v(
    const float* __restrict__ xall, const float* __restrict__ w,
    const float* __restrict__ g,  const float* __restrict__ be,
    const float* __restrict__ mu, const float* __restrict__ va,
    unsigned short* __restrict__ Vf)
{
    __shared__ float ws[32][C];
    const int tid = threadIdx.x;
    const int obk = blockIdx.z;
    const float* wrow = w + (size_t)obk * 32 * C;
    for (int i = tid; i < 32 * C; i += 256) ws[i / C][i % C] = wrow[i];
    __syncthreads();

    const int n = blockIdx.x * 256 + tid;
    const int b = blockIdx.y;
    const float* xb = xall + (size_t)b * 2 * C * NN + n;

    float acc[32];
#pragma unroll
    for (int k = 0; k < 32; k++) acc[k] = 0.f;

    for (int c0 = 0; c0 < C; c0 += 4) {
        const float x0 = xb[(c0 + 0) * NN];
        const float x1 = xb[(c0 + 1) * NN];
        const float x2 = xb[(c0 + 2) * NN];
        const float x3 = xb[(c0 + 3) * NN];
#pragma unroll
        for (int k = 0; k < 32; k++) {
            const float4 wv = *(const float4*)&ws[k][c0];
            acc[k] = fmaf(wv.x, x0, acc[k]);
            acc[k] = fmaf(wv.y, x1, acc[k]);
            acc[k] = fmaf(wv.z, x2, acc[k]);
            acc[k] = fmaf(wv.w, x3, acc[k]);
        }
    }
    unsigned short* op = Vf + (size_t)b * C * NN + n;
#pragma unroll
    for (int k = 0; k < 32; k++) {
        const int o = obk * 32 + k;
        const float sc = g[o] * rsqrtf(va[o] + BN_EPS);
        const float v  = fmaf(acc[k], sc, be[o] - mu[o] * sc);
        op[(size_t)o * NN] = f2bf(v > 0.f ? v : 0.f);
    }
}

// stats: 128(m) x 128(n) KQ tile per block via MFMA; online (max, sumexp) per lane
__global__ __launch_bounds__(256) void k_stats(
    const unsigned short* __restrict__ Kt, const unsigned short* __restrict__ Qt,
    float* __restrict__ bmax, float* __restrict__ bsum)
{
    const int tid = threadIdx.x;
    const int w = tid >> 6, lane = tid & 63;
    const int quad = lane >> 4, l16 = lane & 15;
    const int b = blockIdx.z;
    const int n0 = blockIdx.x * 128, m0 = blockIdx.y * 128;
    const unsigned short* Kb = Kt + (size_t)b * NN * 32;
    const unsigned short* Qb = Qt + (size_t)b * NN * 32;

    bf16x8 kf[8], qf[2];
#pragma unroll
    for (int nt = 0; nt < 8; nt++)
        kf[nt] = *(const bf16x8*)&Kb[(size_t)(n0 + nt * 16 + l16) * 32 + quad * 8];
#pragma unroll
    for (int mt = 0; mt < 2; mt++)
        qf[mt] = *(const bf16x8*)&Qb[(size_t)(m0 + w * 32 + mt * 16 + l16) * 32 + quad * 8];

    float lmax = NEG_INF, lsum = 0.f;
#pragma unroll
    for (int mt = 0; mt < 2; mt++)
#pragma unroll
        for (int nt = 0; nt < 8; nt++) {
            f32x4 s = (f32x4){0.f, 0.f, 0.f, 0.f};
            s = __builtin_amdgcn_mfma_f32_16x16x32_bf16(qf[mt], kf[nt], s, 0, 0, 0);
            const float tmax = fmaxf(fmaxf(s[0], s[1]), fmaxf(s[2], s[3]));
            if (tmax > lmax) { lsum *= __expf(lmax - tmax); lmax = tmax; }
            lsum += __expf(s[0] - lmax) + __expf(s[1] - lmax) +
                    __expf(s[2] - lmax) + __expf(s[3] - lmax);
        }

    // wave butterfly merge
#pragma unroll
    for (int off = 32; off > 0; off >>= 1) {
        const float omax = __shfl_xor(lmax, off);
        const float osum = __shfl_xor(lsum, off);
        const float nmax = fmaxf(lmax, omax);
        lsum = lsum * __expf(lmax - nmax) + osum * __expf(omax - nmax);
        lmax = nmax;
    }
    __shared__ float smax[4], ssum[4];
    if (lane == 0) { smax[w] = lmax; ssum[w] = lsum; }
    __syncthreads();
    if (tid == 0) {
        float M = smax[0], S = ssum[0];
        for (int i = 1; i < 4; i++) {
            const float nmax = fmaxf(M, smax[i]);
            S = S * __expf(M - nmax) + ssum[i] * __expf(smax[i] - nmax);
            M = nmax;
        }
        const int idx = (b * 18 + blockIdx.y) * 18 + blockIdx.x;
        bmax[idx] = M;
        bsum[idx] = S;
    }
}

// finalize per-batch global (M, 1/S)
__global__ __launch_bounds__(256) void k_fin(
    const float* __restrict__ bmax, const float* __restrict__ bsum,
    float* __restrict__ Ms, float* __restrict__ Sinv)
{
    __shared__ float rmax[256], rsum[256];
    const int b = blockIdx.x, tid = threadIdx.x;
    float lmax = NEG_INF, lsum = 0.f;
    for (int i = tid; i < 324; i += 256) {
        const float m = bmax[b * 324 + i], s = bsum[b * 324 + i];
        const float nmax = fmaxf(lmax, m);
        lsum = lsum * __expf(lmax - nmax) + s * __expf(m - nmax);
        lmax = nmax;
    }
    rmax[tid] = lmax; rsum[tid] = lsum;
    __syncthreads();
    for (int st = 128; st > 0; st >>= 1) {
        if (tid < st) {
            const float m2 = rmax[tid + st], s2 = rsum[tid + st];
            const float nmax = fmaxf(rmax[tid], m2);
            rsum[tid] = rsum[tid] * __expf(rmax[tid] - nmax) + s2 * __expf(m2 - nmax);
            rmax[tid] = nmax;
        }
        __syncthreads();
    }
    if (tid == 0) { Ms[b] = rmax[0]; Sinv[b] = 1.f / rsum[0]; }
}

// feat: block = 128(c) x 64(n) output tile; m-chunks of 64:
//   S[m][n] via MFMA (A=Q^T frag, B=K frag) -> exp -> bf16 Et[n][m] in LDS
//   PV: D[c][n] += V-frag x Et-frag (K dim = m)
__global__ __launch_bounds__(256) void k_feat(
    const unsigned short* __restrict__ Kt, const unsigned short* __restrict__ Qt,
    const unsigned short* __restrict__ Vf, const float* __restrict__ Ms,
    const float* __restrict__ Sinv, float* __restrict__ out)
{
    __shared__ __align__(16) unsigned short Et[64][72];  // [n][m], +8 pad
    const int tid = threadIdx.x;
    const int w = tid >> 6, lane = tid & 63;
    const int quad = lane >> 4, l16 = lane & 15;
    const int b = blockIdx.y, n0 = blockIdx.x * 64;
    const unsigned short* Kb = Kt + (size_t)b * NN * 32;
    const unsigned short* Qb = Qt + (size_t)b * NN * 32;
    const unsigned short* Vb = Vf + (size_t)b * C * NN;
    const float M = Ms[b], Si = Sinv[b];

    bf16x8 kf[4];  // block's 64 n, invariant over m-chunks
#pragma unroll
    for (int nt = 0; nt < 4; nt++)
        kf[nt] = *(const bf16x8*)&Kb[(size_t)(n0 + nt * 16 + l16) * 32 + quad * 8];

    f32x4 acc[2][4];
#pragma unroll
    for (int i = 0; i < 2; i++)
#pragma unroll
        for (int j = 0; j < 4; j++) acc[i][j] = (f32x4){0.f, 0.f, 0.f, 0.f};

    for (int m0 = 0; m0 < NN; m0 += 64) {
        // S phase: wave w computes m rows [m0+16w, +16)
        const bf16x8 qf = *(const bf16x8*)&Qb[(size_t)(m0 + w * 16 + l16) * 32 + quad * 8];
#pragma unroll
        for (int nt = 0; nt < 4; nt++) {
            f32x4 s = (f32x4){0.f, 0.f, 0.f, 0.f};
            s = __builtin_amdgcn_mfma_f32_16x16x32_bf16(qf, kf[nt], s, 0, 0, 0);
            // lane holds (m = m0 + 16w + quad*4 + r, n = n0 + nt*16 + l16)
            const unsigned int p0 = (unsigned int)f2bf(__expf(s[0] - M)) |
                                    ((unsigned int)f2bf(__expf(s[1] - M)) << 16);
            const unsigned int p1 = (unsigned int)f2bf(__expf(s[2] - M)) |
                                    ((unsigned int)f2bf(__expf(s[3] - M)) << 16);
            *(uint2*)&Et[nt * 16 + l16][w * 16 + quad * 4] = make_uint2(p0, p1);
        }
        __syncthreads();
        // PV phase: wave w -> c in [32w, 32w+32)
#pragma unroll
        for (int ks = 0; ks < 2; ks++) {
            const bf16x8 va = *(const bf16x8*)&Vb[(size_t)(w * 32 + l16) * NN + m0 + ks * 32 + quad * 8];
            const bf16x8 vb = *(const bf16x8*)&Vb[(size_t)(w * 32 + 16 + l16) * NN + m0 + ks * 32 + quad * 8];
#pragma unroll
            for (int nt = 0; nt < 4; nt++) {
                const bf16x8 ef = *(const bf16x8*)&Et[nt * 16 + l16][ks * 32 + quad * 8];
                acc[0][nt] = __builtin_amdgcn_mfma_f32_16x16x32_bf16(va, ef, acc[0][nt], 0, 0, 0);
                acc[1][nt] = __builtin_amdgcn_mfma_f32_16x16x32_bf16(vb, ef, acc[1][nt], 0, 0, 0);
            }
        }
        __syncthreads();
    }

    float* ob = out + (size_t)b * 2 * C * NN + (size_t)C * NN + n0;
#pragma unroll
    for (int ct = 0; ct < 2; ct++)
#pragma unroll
        for (int nt = 0; nt < 4; nt++)
#pragma unroll
            for (int r = 0; r < 4; r++) {
                const int c = w * 32 + ct * 16 + quad * 4 + r;
                ob[(size_t)c * NN + nt * 16 + l16] = acc[ct][nt][r] * Si;
            }
}

extern "C" void kernel_launch(void* const* d_in, const int* in_sizes, int n_in,
                              void* d_out, int out_size, void* d_ws, size_t ws_size,
                              hipStream_t stream)
{
    const float* x_en   = (const float*)d_in[0];
    const float* x_de   = (const float*)d_in[1];
    const float* x_cat  = (const float*)d_in[2];
    const float* w_kq   = (const float*)d_in[3];
    const float* kq_g   = (const float*)d_in[4];
    const float* kq_b   = (const float*)d_in[5];
    const float* kq_m   = (const float*)d_in[6];
    const float* kq_v   = (const float*)d_in[7];
    const float* w_v    = (const float*)d_in[8];
    const float* v_g    = (const float*)d_in[9];
    const float* v_b    = (const float*)d_in[10];
    const float* v_m    = (const float*)d_in[11];
    const float* v_v    = (const float*)d_in[12];
    const float* w_red  = (const float*)d_in[13];
    const float* red_g  = (const float*)d_in[14];
    const float* red_b  = (const float*)d_in[15];
    const float* red_m  = (const float*)d_in[16];
    const float* red_v  = (const float*)d_in[17];

    unsigned short* Kt = (unsigned short*)d_ws;
    unsigned short* Qt = Kt + 1179648;
    unsigned short* Vf = Qt + 1179648;
    float* bmax = (float*)(Vf + 4718592);
    float* bsum = bmax + 16 * 324;
    float* Ms   = bsum + 16 * 324;
    float* Sinv = Ms + 16;
    float* out  = (float*)d_out;

    k_kq   <<<dim3(9, 16, 2), 256, 0, stream>>>(x_en, x_de, w_kq, kq_g, kq_b, kq_m, kq_v, Kt, Qt);
    k_red  <<<dim3(9, 16, 4), 256, 0, stream>>>(x_cat, w_red, red_g, red_b, red_m, red_v, out);
    k_v    <<<dim3(9, 16, 4), 256, 0, stream>>>(out, w_v, v_g, v_b, v_m, v_v, Vf);
    k_stats<<<dim3(18, 18, 16), 256, 0, stream>>>(Kt, Qt, bmax, bsum);
    k_fin  <<<16, 256, 0, stream>>>(bmax, bsum, Ms, Sinv);
    k_feat <<<dim3(36, 16), 256, 0, stream>>>(Kt, Qt, Vf, Ms, Sinv, out);
}

// Round 3
// 275.786 us; speedup vs baseline: 3.0551x; 1.4251x over previous
//
#include <hip/hip_runtime.h>
#include <math.h>

#define C    128
#define C4   32
#define NN   2304          // 48*48
#define BN_EPS 1e-5f
#define NEG_INF -3.402823466e38f

typedef short bf16x8 __attribute__((ext_vector_type(8)));
typedef float f32x4 __attribute__((ext_vector_type(4)));

__device__ inline unsigned short f2bf(float f) {
    unsigned int u = __float_as_uint(f);
    u += 0x7fffu + ((u >> 16) & 1u);
    return (unsigned short)(u >> 16);
}

// ---------------- workspace layout ----------------
// ushort region:
//   Kt  [16][2304][32]  @0         (1179648)
//   Qt  [16][2304][32]  @1179648   (1179648)
//   Vf  [16][128][2304] @2359296   (4718592)
//   wkq_bf [32][128]    @7077888   (4096)
//   wv_bf  [128][128]   @7081984   (16384)
//   wred_bf[128][256]   @7098368   (32768)
// float region @ushort 7131136 (byte 14262272):
//   bmax[16*324], bsum[16*324], Ms[16], Sinv[16], kq_sh[32], v_sh[128], red_sh[128]

// ---- weight prep: fold BN scale into bf16 weights, compute shifts ----
__global__ __launch_bounds__(256) void k_wprep(
    const float* __restrict__ wkq, const float* __restrict__ kq_g,
    const float* __restrict__ kq_b, const float* __restrict__ kq_m,
    const float* __restrict__ kq_v,
    const float* __restrict__ wv, const float* __restrict__ v_g,
    const float* __restrict__ v_b, const float* __restrict__ v_m,
    const float* __restrict__ v_v,
    const float* __restrict__ wred, const float* __restrict__ red_g,
    const float* __restrict__ red_b, const float* __restrict__ red_m,
    const float* __restrict__ red_v,
    unsigned short* __restrict__ wkq_bf, unsigned short* __restrict__ wv_bf,
    unsigned short* __restrict__ wred_bf,
    float* __restrict__ kq_sh, float* __restrict__ v_sh, float* __restrict__ red_sh)
{
    const int t = blockIdx.x * 256 + threadIdx.x;
    if (t < 4096) {
        const int o = t >> 7;
        const float sc = kq_g[o] * rsqrtf(kq_v[o] + BN_EPS);
        wkq_bf[t] = f2bf(wkq[t] * sc);
        if ((t & 127) == 0) kq_sh[o] = kq_b[o] - kq_m[o] * sc;
    } else if (t < 4096 + 16384) {
        const int e = t - 4096;
        const int o = e >> 7;
        const float sc = v_g[o] * rsqrtf(v_v[o] + BN_EPS);
        wv_bf[e] = f2bf(wv[e] * sc);
        if ((e & 127) == 0) v_sh[o] = v_b[o] - v_m[o] * sc;
    } else if (t < 4096 + 16384 + 32768) {
        const int e = t - 20480;
        const int o = e >> 8;
        const float sc = red_g[o] * rsqrtf(red_v[o] + BN_EPS);
        wred_bf[e] = f2bf(wred[e] * sc);
        if ((e & 255) == 0) red_sh[o] = red_b[o] - red_m[o] * sc;
    }
}

// ---- unified MFMA 1x1-conv kernel ----
// MODE 0: fp32 out rows [b][o][n] into outf (+b*2C*NN)      (reduce conv)
// MODE 1: bf16 out  [b][o][n] into outb0 (Vf)               (V conv)
// MODE 2: bf16 transposed [b][n][32o] into outb0/outb1      (K/Q conv, z picks)
template<int CIN, int M, int NTILE, int MODE>
__global__ __launch_bounds__(256) void k_conv(
    const float* __restrict__ x0, const float* __restrict__ x1, size_t xbstride,
    const unsigned short* __restrict__ wbf, const float* __restrict__ shift,
    float* __restrict__ outf, unsigned short* __restrict__ outb0,
    unsigned short* __restrict__ outb1)
{
    constexpr int R  = NTILE / 16;     // rows of X per staging thread
    constexpr int MT = 2;
    constexpr int NT = (M == 32) ? 2 : (NTILE / 16);
    __shared__ unsigned short Xs[NTILE][40];   // [n][32c], stride 40 -> 2-way-free banks

    const int tid = threadIdx.x;
    const int w = tid >> 6, lane = tid & 63;
    const int quad = lane >> 4, l16 = lane & 15;
    const int b = blockIdx.y, n0 = blockIdx.x * NTILE;
    const int mbase = (M == 32) ? 0 : w * 32;
    const int nbase = (M == 32) ? w * 32 : 0;

    const float* xin = (blockIdx.z ? x1 : x0) + (size_t)b * xbstride;
    const int p = tid & 15, g = tid >> 4;

    f32x4 acc[MT][NT];
#pragma unroll
    for (int mt = 0; mt < MT; mt++)
#pragma unroll
        for (int nt = 0; nt < NT; nt++) acc[mt][nt] = (f32x4){0.f, 0.f, 0.f, 0.f};

    for (int c0 = 0; c0 < CIN; c0 += 32) {
        __syncthreads();
        {   // stage: thread handles c-pair (c0+2p, c0+2p+1) x R consecutive n
            const float* xr = xin + (size_t)(c0 + 2 * p) * NN + n0 + g * R;
            float av[R], bv[R];
#pragma unroll
            for (int i4 = 0; i4 < R; i4 += 4) {
                *(float4*)&av[i4] = *(const float4*)&xr[i4];
                *(float4*)&bv[i4] = *(const float4*)&xr[NN + i4];
            }
            unsigned int* Xw = (unsigned int*)Xs;
#pragma unroll
            for (int i = 0; i < R; i++)
                Xw[(g * R + i) * 20 + p] =
                    (unsigned int)f2bf(av[i]) | ((unsigned int)f2bf(bv[i]) << 16);
        }
        __syncthreads();
        bf16x8 af[MT];
#pragma unroll
        for (int mt = 0; mt < MT; mt++)
            af[mt] = *(const bf16x8*)&wbf[(size_t)(mbase + mt * 16 + l16) * CIN + c0 + quad * 8];
#pragma unroll
        for (int nt = 0; nt < NT; nt++) {
            const bf16x8 bfr = *(const bf16x8*)&Xs[nbase + nt * 16 + l16][quad * 8];
#pragma unroll
            for (int mt = 0; mt < MT; mt++)
                acc[mt][nt] = __builtin_amdgcn_mfma_f32_16x16x32_bf16(af[mt], bfr, acc[mt][nt], 0, 0, 0);
        }
    }

    float sh[MT][4];
#pragma unroll
    for (int mt = 0; mt < MT; mt++)
#pragma unroll
        for (int r = 0; r < 4; r++) sh[mt][r] = shift[mbase + mt * 16 + quad * 4 + r];

    if (MODE == 0) {
        float* ob = outf + (size_t)b * (2 * C * NN);
#pragma unroll
        for (int mt = 0; mt < MT; mt++)
#pragma unroll
            for (int nt = 0; nt < NT; nt++)
#pragma unroll
                for (int r = 0; r < 4; r++) {
                    const int o = mbase + mt * 16 + quad * 4 + r;
                    const int n = n0 + nbase + nt * 16 + l16;
                    ob[(size_t)o * NN + n] = fmaxf(acc[mt][nt][r] + sh[mt][r], 0.f);
                }
    } else if (MODE == 1) {
#pragma unroll
        for (int mt = 0; mt < MT; mt++)
#pragma unroll
            for (int nt = 0; nt < NT; nt++)
#pragma unroll
                for (int r = 0; r < 4; r++) {
                    const int o = mbase + mt * 16 + quad * 4 + r;
                    const int n = n0 + nbase + nt * 16 + l16;
                    outb0[((size_t)b * C + o) * NN + n] = f2bf(fmaxf(acc[mt][nt][r] + sh[mt][r], 0.f));
                }
    } else {
        unsigned short* ob16 = blockIdx.z ? outb1 : outb0;
#pragma unroll
        for (int mt = 0; mt < MT; mt++)
#pragma unroll
            for (int nt = 0; nt < NT; nt++)
#pragma unroll
                for (int r = 0; r < 4; r++) {
                    const int o = mbase + mt * 16 + quad * 4 + r;
                    const int n = n0 + nbase + nt * 16 + l16;
                    ob16[((size_t)b * NN + n) * 32 + o] = f2bf(fmaxf(acc[mt][nt][r] + sh[mt][r], 0.f));
                }
    }
}

// stats: 128(m) x 128(n) KQ tile per block via MFMA; online (max, sumexp) per lane
__global__ __launch_bounds__(256) void k_stats(
    const unsigned short* __restrict__ Kt, const unsigned short* __restrict__ Qt,
    float* __restrict__ bmax, float* __restrict__ bsum)
{
    const int tid = threadIdx.x;
    const int w = tid >> 6, lane = tid & 63;
    const int quad = lane >> 4, l16 = lane & 15;
    const int b = blockIdx.z;
    const int n0 = blockIdx.x * 128, m0 = blockIdx.y * 128;
    const unsigned short* Kb = Kt + (size_t)b * NN * 32;
    const unsigned short* Qb = Qt + (size_t)b * NN * 32;

    bf16x8 kf[8], qf[2];
#pragma unroll
    for (int nt = 0; nt < 8; nt++)
        kf[nt] = *(const bf16x8*)&Kb[(size_t)(n0 + nt * 16 + l16) * 32 + quad * 8];
#pragma unroll
    for (int mt = 0; mt < 2; mt++)
        qf[mt] = *(const bf16x8*)&Qb[(size_t)(m0 + w * 32 + mt * 16 + l16) * 32 + quad * 8];

    float lmax = NEG_INF, lsum = 0.f;
#pragma unroll
    for (int mt = 0; mt < 2; mt++)
#pragma unroll
        for (int nt = 0; nt < 8; nt++) {
            f32x4 s = (f32x4){0.f, 0.f, 0.f, 0.f};
            s = __builtin_amdgcn_mfma_f32_16x16x32_bf16(qf[mt], kf[nt], s, 0, 0, 0);
            const float tmax = fmaxf(fmaxf(s[0], s[1]), fmaxf(s[2], s[3]));
            if (tmax > lmax) { lsum *= __expf(lmax - tmax); lmax = tmax; }
            lsum += __expf(s[0] - lmax) + __expf(s[1] - lmax) +
                    __expf(s[2] - lmax) + __expf(s[3] - lmax);
        }

#pragma unroll
    for (int off = 32; off > 0; off >>= 1) {
        const float omax = __shfl_xor(lmax, off);
        const float osum = __shfl_xor(lsum, off);
        const float nmax = fmaxf(lmax, omax);
        lsum = lsum * __expf(lmax - nmax) + osum * __expf(omax - nmax);
        lmax = nmax;
    }
    __shared__ float smax[4], ssum[4];
    if (lane == 0) { smax[w] = lmax; ssum[w] = lsum; }
    __syncthreads();
    if (tid == 0) {
        float M = smax[0], S = ssum[0];
        for (int i = 1; i < 4; i++) {
            const float nmax = fmaxf(M, smax[i]);
            S = S * __expf(M - nmax) + ssum[i] * __expf(smax[i] - nmax);
            M = nmax;
        }
        const int idx = (b * 18 + blockIdx.y) * 18 + blockIdx.x;
        bmax[idx] = M;
        bsum[idx] = S;
    }
}

// finalize per-batch global (M, 1/S)
__global__ __launch_bounds__(256) void k_fin(
    const float* __restrict__ bmax, const float* __restrict__ bsum,
    float* __restrict__ Ms, float* __restrict__ Sinv)
{
    __shared__ float rmax[256], rsum[256];
    const int b = blockIdx.x, tid = threadIdx.x;
    float lmax = NEG_INF, lsum = 0.f;
    for (int i = tid; i < 324; i += 256) {
        const float m = bmax[b * 324 + i], s = bsum[b * 324 + i];
        const float nmax = fmaxf(lmax, m);
        lsum = lsum * __expf(lmax - nmax) + s * __expf(m - nmax);
        lmax = nmax;
    }
    rmax[tid] = lmax; rsum[tid] = lsum;
    __syncthreads();
    for (int st = 128; st > 0; st >>= 1) {
        if (tid < st) {
            const float m2 = rmax[tid + st], s2 = rsum[tid + st];
            const float nmax = fmaxf(rmax[tid], m2);
            rsum[tid] = rsum[tid] * __expf(rmax[tid] - nmax) + s2 * __expf(m2 - nmax);
            rmax[tid] = nmax;
        }
        __syncthreads();
    }
    if (tid == 0) { Ms[b] = rmax[0]; Sinv[b] = 1.f / rsum[0]; }
}

// feat: block = 128(c) x 64(n) output tile; m-chunks of 64
__global__ __launch_bounds__(256) void k_feat(
    const unsigned short* __restrict__ Kt, const unsigned short* __restrict__ Qt,
    const unsigned short* __restrict__ Vf, const float* __restrict__ Ms,
    const float* __restrict__ Sinv, float* __restrict__ out)
{
    __shared__ __align__(16) unsigned short Et[64][72];
    const int tid = threadIdx.x;
    const int w = tid >> 6, lane = tid & 63;
    const int quad = lane >> 4, l16 = lane & 15;
    const int b = blockIdx.y, n0 = blockIdx.x * 64;
    const unsigned short* Kb = Kt + (size_t)b * NN * 32;
    const unsigned short* Qb = Qt + (size_t)b * NN * 32;
    const unsigned short* Vb = Vf + (size_t)b * C * NN;
    const float M = Ms[b], Si = Sinv[b];

    bf16x8 kf[4];
#pragma unroll
    for (int nt = 0; nt < 4; nt++)
        kf[nt] = *(const bf16x8*)&Kb[(size_t)(n0 + nt * 16 + l16) * 32 + quad * 8];

    f32x4 acc[2][4];
#pragma unroll
    for (int i = 0; i < 2; i++)
#pragma unroll
        for (int j = 0; j < 4; j++) acc[i][j] = (f32x4){0.f, 0.f, 0.f, 0.f};

    for (int m0 = 0; m0 < NN; m0 += 64) {
        const bf16x8 qf = *(const bf16x8*)&Qb[(size_t)(m0 + w * 16 + l16) * 32 + quad * 8];
#pragma unroll
        for (int nt = 0; nt < 4; nt++) {
            f32x4 s = (f32x4){0.f, 0.f, 0.f, 0.f};
            s = __builtin_amdgcn_mfma_f32_16x16x32_bf16(qf, kf[nt], s, 0, 0, 0);
            const unsigned int p0 = (unsigned int)f2bf(__expf(s[0] - M)) |
                                    ((unsigned int)f2bf(__expf(s[1] - M)) << 16);
            const unsigned int p1 = (unsigned int)f2bf(__expf(s[2] - M)) |
                                    ((unsigned int)f2bf(__expf(s[3] - M)) << 16);
            *(uint2*)&Et[nt * 16 + l16][w * 16 + quad * 4] = make_uint2(p0, p1);
        }
        __syncthreads();
#pragma unroll
        for (int ks = 0; ks < 2; ks++) {
            const bf16x8 va = *(const bf16x8*)&Vb[(size_t)(w * 32 + l16) * NN + m0 + ks * 32 + quad * 8];
            const bf16x8 vb = *(const bf16x8*)&Vb[(size_t)(w * 32 + 16 + l16) * NN + m0 + ks * 32 + quad * 8];
#pragma unroll
            for (int nt = 0; nt < 4; nt++) {
                const bf16x8 ef = *(const bf16x8*)&Et[nt * 16 + l16][ks * 32 + quad * 8];
                acc[0][nt] = __builtin_amdgcn_mfma_f32_16x16x32_bf16(va, ef, acc[0][nt], 0, 0, 0);
                acc[1][nt] = __builtin_amdgcn_mfma_f32_16x16x32_bf16(vb, ef, acc[1][nt], 0, 0, 0);
            }
        }
        __syncthreads();
    }

    float* ob = out + (size_t)b * 2 * C * NN + (size_t)C * NN + n0;
#pragma unroll
    for (int ct = 0; ct < 2; ct++)
#pragma unroll
        for (int nt = 0; nt < 4; nt++)
#pragma unroll
            for (int r = 0; r < 4; r++) {
                const int c = w * 32 + ct * 16 + quad * 4 + r;
                ob[(size_t)c * NN + nt * 16 + l16] = acc[ct][nt][r] * Si;
            }
}

extern "C" void kernel_launch(void* const* d_in, const int* in_sizes, int n_in,
                              void* d_out, int out_size, void* d_ws, size_t ws_size,
                              hipStream_t stream)
{
    const float* x_en   = (const float*)d_in[0];
    const float* x_de   = (const float*)d_in[1];
    const float* x_cat  = (const float*)d_in[2];
    const float* w_kq   = (const float*)d_in[3];
    const float* kq_g   = (const float*)d_in[4];
    const float* kq_b   = (const float*)d_in[5];
    const float* kq_m   = (const float*)d_in[6];
    const float* kq_v   = (const float*)d_in[7];
    const float* w_v    = (const float*)d_in[8];
    const float* v_g    = (const float*)d_in[9];
    const float* v_b    = (const float*)d_in[10];
    const float* v_m    = (const float*)d_in[11];
    const float* v_v    = (const float*)d_in[12];
    const float* w_red  = (const float*)d_in[13];
    const float* red_g  = (const float*)d_in[14];
    const float* red_b  = (const float*)d_in[15];
    const float* red_m  = (const float*)d_in[16];
    const float* red_v  = (const float*)d_in[17];

    unsigned short* Kt      = (unsigned short*)d_ws;
    unsigned short* Qt      = Kt + 1179648;
    unsigned short* Vf      = Qt + 1179648;
    unsigned short* wkq_bf  = Vf + 4718592;
    unsigned short* wv_bf   = wkq_bf + 4096;
    unsigned short* wred_bf = wv_bf + 16384;
    float* bmax = (float*)(wred_bf + 32768);
    float* bsum = bmax + 16 * 324;
    float* Ms   = bsum + 16 * 324;
    float* Sinv = Ms + 16;
    float* kq_sh  = Sinv + 16;
    float* v_sh   = kq_sh + 32;
    float* red_sh = v_sh + 128;
    float* out  = (float*)d_out;

    k_wprep<<<208, 256, 0, stream>>>(
        w_kq, kq_g, kq_b, kq_m, kq_v,
        w_v, v_g, v_b, v_m, v_v,
        w_red, red_g, red_b, red_m, red_v,
        wkq_bf, wv_bf, wred_bf, kq_sh, v_sh, red_sh);

    k_conv<128, 32, 128, 2><<<dim3(18, 16, 2), 256, 0, stream>>>(
        x_en, x_de, (size_t)C * NN, wkq_bf, kq_sh, nullptr, Kt, Qt);
    k_conv<256, 128, 64, 0><<<dim3(36, 16), 256, 0, stream>>>(
        x_cat, nullptr, (size_t)(2 * C) * NN, wred_bf, red_sh, out, nullptr, nullptr);
    k_conv<128, 128, 64, 1><<<dim3(36, 16), 256, 0, stream>>>(
        out, nullptr, (size_t)(2 * C) * NN, wv_bf, v_sh, nullptr, Vf, nullptr);

    k_stats<<<dim3(18, 18, 16), 256, 0, stream>>>(Kt, Qt, bmax, bsum);
    k_fin  <<<16, 256, 0, stream>>>(bmax, bsum, Ms, Sinv);
    k_feat <<<dim3(36, 16), 256, 0, stream>>>(Kt, Qt, Vf, Ms, Sinv, out);
}